// Round 2
// baseline (255.689 us; speedup 1.0000x reference)
//
#include <hip/hip_runtime.h>
#include <math.h>

#define G 8
#define Hd 256
#define Wd 256
#define HW (Hd * Wd)

typedef float fvec4 __attribute__((ext_vector_type(4)));

// ---------------------------------------------------------------------------
// v3: cross-image software pipeline. 256 blocks x 1024 thr; block B owns
// images 2B and 2B+1. Phases per block:
//   GLCM(2B) -> wplus0 -> GLCM(2B+1) || scale-stores(2B) -> wplus1 -> scale(2B+1)
// The scale of image 2B is interleaved into image 2B+1's GLCM row loop
// (1 float4 per lane per row-iteration, 16 slots = full image): its L3-hit
// loads + nontemporal stores ride the memory pipe under the ballot/popcount
// VALU work, de-serializing the compute and stream phases.
//
// GLCM core (verified in v2, unchanged math):
//   wave's 64 lanes = 64 consecutive columns, 4 segments cover 256 cols.
//   Lane L owns bin L (i = L>>3, j = L&7).
//   mjl/mjr are single shifts of the COMPOSED j-match mask MJ
//     (mk_mj(B<<1) == (mk_mj(B)<<1) | carry, zero-pad bit0 = (j==0)).
//   mi is a lane permutation of MJ: mi[L] = MJ[L>>3] via ds_bpermute pair,
//     consumed one row later (cnt0 deferred through MJL_prev).
// Pair semantics (d=1, angles 0, pi/4, pi/2, 3pi/4), zero-padded borders;
// OOB neighbor -> q=0 -> bin j=0 (JL0/JR0 carries, MJPAD pad row).
// ---------------------------------------------------------------------------
__global__ __launch_bounds__(1024) void glcm_fused2(const float* __restrict__ x,
                                                    const float* __restrict__ W1,
                                                    const float* __restrict__ W2,
                                                    float* __restrict__ out) {
    __shared__ unsigned int hist[4 * 64];   // [angle][i*8+j]
    __shared__ float feats_s[16];
    __shared__ float h_s[16];
    __shared__ float w_s;

    const int t = threadIdx.x;
    const int lane = t & 63;
    const int wv = t >> 6;                  // 0..15
    const int r0 = wv << 4;                 // first owned row

    // j-selectors (j = lane&7): XNOR-select composition of ballot bitplanes.
    const unsigned long long F0 = (lane & 1) ? 0ull : ~0ull;
    const unsigned long long F1 = (lane & 2) ? 0ull : ~0ull;
    const unsigned long long F2 = (lane & 4) ? 0ull : ~0ull;
    const unsigned long long MJPAD = F0 & F1 & F2;        // mask of a zero-pad row
    const unsigned long long JL0 = MJPAD & 1ull;          // bit0 after <<1 at s=0
    const unsigned long long JR0 = MJPAD & (1ull << 63);  // bit63 after >>1 at s=3
    const int baddr = (lane >> 3) << 2;     // ds_bpermute byte addr: lane i(L)

    float wprev = 0.0f;                     // wplus of image 2B (set after p=0)

    #pragma unroll
    for (int p = 0; p < 2; ++p) {
        const int bc = (blockIdx.x << 1) | p;
        const float* img = x + (size_t)bc * HW;

        // previous image's scale pointers (only used when p==1)
        const fvec4* simg4 = (const fvec4*)(x + (size_t)(bc - 1) * HW);
        fvec4* sout4 = (fvec4*)(out + (size_t)(bc - 1) * HW);
        const int sbase = (wv << 10) + lane;   // wave's float4 region

        if (t < 256) hist[t] = 0u;

        unsigned int cnt0 = 0, cnt1 = 0, cnt2 = 0, cnt3 = 0;
        unsigned long long MJ[4], Mi_prev[4], MJL_prev[4];
        float vc[4], vn[4];

        auto bperm64 = [&](unsigned long long v) -> unsigned long long {
            const unsigned int lo =
                (unsigned int)__builtin_amdgcn_ds_bpermute(baddr, (int)(unsigned int)v);
            const unsigned int hi =
                (unsigned int)__builtin_amdgcn_ds_bpermute(baddr, (int)(unsigned int)(v >> 32));
            return ((unsigned long long)hi << 32) | lo;
        };
        auto make_mj = [&]() {
            #pragma unroll
            for (int s = 0; s < 4; ++s) {
                const int q = (int)(vc[s] * 7.0f);
                const unsigned long long b0 = __ballot(q & 1);
                const unsigned long long b1 = __ballot(q & 2);
                const unsigned long long b2 = __ballot(q & 4);
                MJ[s] = (b0 ^ F0) & (b1 ^ F1) & (b2 ^ F2);
            }
        };

        // ---- prologue: row r0 (cnt0 of row y is deferred to iteration y+1) ----
        #pragma unroll
        for (int s = 0; s < 4; ++s) vc[s] = img[r0 * Wd + (s << 6) + lane];
        #pragma unroll
        for (int s = 0; s < 4; ++s) vn[s] = img[(r0 + 1) * Wd + (s << 6) + lane];
        make_mj();
        #pragma unroll
        for (int s = 0; s < 4; ++s) {
            MJL_prev[s] = (MJ[s] << 1) | (s ? (MJ[s - 1] >> 63) : JL0);
            Mi_prev[s] = bperm64(MJ[s]);
        }

        // ---- rows r0+1 .. r0+15 (scale slot k = yy-1 when p==1) ----
        for (int yy = 1; yy < 16; ++yy) {
            fvec4 sv;
            if (p == 1) sv = simg4[sbase + ((yy - 1) << 6)];   // L3 hit
            #pragma unroll
            for (int s = 0; s < 4; ++s) vc[s] = vn[s];
            const int yn = r0 + yy + 1;
            if (yn < Hd) {                  // wave-uniform guard (last wave, yy==15)
                #pragma unroll
                for (int s = 0; s < 4; ++s) vn[s] = img[yn * Wd + (s << 6) + lane];
            }
            make_mj();
            #pragma unroll
            for (int s = 0; s < 4; ++s) {
                const unsigned long long mjl = (MJ[s] << 1) | (s ? (MJ[s - 1] >> 63) : JL0);
                const unsigned long long mjr = (MJ[s] >> 1) | (s < 3 ? (MJ[s + 1] << 63) : JR0);
                cnt0 += __popcll(Mi_prev[s] & MJL_prev[s]);   // angle0 of row yy-1
                cnt1 += __popcll(Mi_prev[s] & mjl);
                cnt2 += __popcll(Mi_prev[s] & MJ[s]);
                cnt3 += __popcll(Mi_prev[s] & mjr);
                MJL_prev[s] = mjl;
            }
            #pragma unroll
            for (int s = 0; s < 4; ++s) Mi_prev[s] = bperm64(MJ[s]);
            if (p == 1) {
                sv *= wprev;
                __builtin_nontemporal_store(sv, &sout4[sbase + ((yy - 1) << 6)]);
            }
        }

        // ---- boundary row r0+16 (next wave's first row, or zero pad);
        //      scale slot k=15 when p==1 ----
        fvec4 svb;
        if (p == 1) svb = simg4[sbase + (15 << 6)];
        if (r0 + 16 < Hd) {
            #pragma unroll
            for (int s = 0; s < 4; ++s) vc[s] = vn[s];
            make_mj();
        } else {
            #pragma unroll
            for (int s = 0; s < 4; ++s) MJ[s] = MJPAD;
        }
        #pragma unroll
        for (int s = 0; s < 4; ++s) {
            const unsigned long long mjl = (MJ[s] << 1) | (s ? (MJ[s - 1] >> 63) : JL0);
            const unsigned long long mjr = (MJ[s] >> 1) | (s < 3 ? (MJ[s + 1] << 63) : JR0);
            cnt0 += __popcll(Mi_prev[s] & MJL_prev[s]);       // angle0 of row r0+15
            cnt1 += __popcll(Mi_prev[s] & mjl);
            cnt2 += __popcll(Mi_prev[s] & MJ[s]);
            cnt3 += __popcll(Mi_prev[s] & mjr);
        }
        if (p == 1) {
            svb *= wprev;
            __builtin_nontemporal_store(svb, &sout4[sbase + (15 << 6)]);
        }

        __syncthreads();                    // hist init visible
        atomicAdd(&hist[  0 + lane], cnt0);
        atomicAdd(&hist[ 64 + lane], cnt1);
        atomicAdd(&hist[128 + lane], cnt2);
        atomicAdd(&hist[192 + lane], cnt3);
        __syncthreads();

        // ---- features: wave a (t<256) handles angle a; 64 bins = 64 lanes ----
        if (t < 256) {
            float csum, hsum, esum, rsum;
            {
                const int a = t >> 6;
                const int bin = t & 63;
                const float pr = (float)hist[a * 64 + bin] * (1.0f / 65536.0f);
                const int i = bin >> 3, j = bin & 7;
                const int dij = i - j;
                const int adij = dij < 0 ? -dij : dij;
                csum = (float)(dij * dij) * pr;
                hsum = pr / (float)(1 + adij);
                esum = pr * pr;
                rsum = ((float)i - 3.5f) * ((float)j - 3.5f) * pr;
            }
            #pragma unroll
            for (int m = 1; m < 64; m <<= 1) {
                csum += __shfl_xor(csum, m, 64);
                hsum += __shfl_xor(hsum, m, 64);
                esum += __shfl_xor(esum, m, 64);
                rsum += __shfl_xor(rsum, m, 64);
            }
            if ((t & 63) == 0) {
                const int a = t >> 6;
                feats_s[a * 4 + 0] = csum;
                feats_s[a * 4 + 1] = hsum;
                feats_s[a * 4 + 2] = esum;
                // I_STD^2 + 1e-6, I_STD = sqrt(6) (ddof=1 std of arange(8))
                feats_s[a * 4 + 3] = rsum * (1.0f / 6.000001f);
            }
        }
        __syncthreads();

        // ---- MLP: h = relu(feats @ W1); z = h @ W2[:, c]; w = sigmoid(z) ----
        if (t < 16) {
            float acc = 0.0f;
            #pragma unroll
            for (int f = 0; f < 16; ++f) acc += feats_s[f] * W1[f * 16 + t];
            h_s[t] = acc > 0.0f ? acc : 0.0f;
        }
        __syncthreads();
        if (t == 0) {
            const int c = bc & 63;
            float z = 0.0f;
            #pragma unroll
            for (int k = 0; k < 16; ++k) z += h_s[k] * W2[k * 64 + c];
            w_s = 1.0f + 1.0f / (1.0f + expf(-z));
        }
        __syncthreads();

        if (p == 0) {
            wprev = w_s;                    // consumed by p=1's interleaved scale
        } else {
            // ---- tail: scale image 2B+1 (L3-resident re-read), 4-wide batches ----
            const float w = w_s;
            const fvec4* img4 = (const fvec4*)img;
            fvec4* out4 = (fvec4*)(out + (size_t)bc * HW);
            #pragma unroll
            for (int k = 0; k < 16; k += 4) {
                fvec4 a = img4[(k + 0) * 1024 + t];
                fvec4 b = img4[(k + 1) * 1024 + t];
                fvec4 c = img4[(k + 2) * 1024 + t];
                fvec4 d = img4[(k + 3) * 1024 + t];
                a *= w; b *= w; c *= w; d *= w;
                __builtin_nontemporal_store(a, &out4[(k + 0) * 1024 + t]);
                __builtin_nontemporal_store(b, &out4[(k + 1) * 1024 + t]);
                __builtin_nontemporal_store(c, &out4[(k + 2) * 1024 + t]);
                __builtin_nontemporal_store(d, &out4[(k + 3) * 1024 + t]);
            }
        }
    }
}

extern "C" void kernel_launch(void* const* d_in, const int* in_sizes, int n_in,
                              void* d_out, int out_size, void* d_ws, size_t ws_size,
                              hipStream_t stream) {
    (void)in_sizes; (void)n_in; (void)d_ws; (void)ws_size; (void)out_size;
    const float* x  = (const float*)d_in[0];
    const float* W1 = (const float*)d_in[1];   // (16,16) row-major
    const float* W2 = (const float*)d_in[2];   // (16,64) row-major
    float* out = (float*)d_out;

    glcm_fused2<<<256, 1024, 0, stream>>>(x, W1, W2, out);
}